// Round 5
// baseline (555.554 us; speedup 1.0000x reference)
//
#include <hip/hip_runtime.h>
#include <hip/hip_bf16.h>
#include <hip/hip_fp16.h>

#define FDIM 64
#define SEG 512           // counters per scan segment

__device__ __forceinline__ int clampi(int v, int n) { return min(max(v, 0), n - 1); }

// ---- CSR build, phase 1: per-node edge counts via global atomics -----------
// cnt[2N]: layer0 at [0,N), layer1 at [N,2N). Zeroed before launch.
// int4 loads (E%4==0, pointers 16B-aligned).
__global__ __launch_bounds__(256) void count_edges(
    const int* __restrict__ c0, const int* __restrict__ c1,
    int* __restrict__ cnt, int n, int E)
{
    int gid = blockIdx.x * 256 + threadIdx.x;
    int stride = gridDim.x * 256;
    int q = E >> 2;
    for (int i = gid; i < q; i += stride) {
        int4 v = ((const int4*)c0)[i];
        atomicAdd(&cnt[clampi(v.x, n)], 1);
        atomicAdd(&cnt[clampi(v.y, n)], 1);
        atomicAdd(&cnt[clampi(v.z, n)], 1);
        atomicAdd(&cnt[clampi(v.w, n)], 1);
    }
    for (int i = gid; i < q; i += stride) {
        int4 v = ((const int4*)c1)[i];
        atomicAdd(&cnt[n + clampi(v.x, n)], 1);
        atomicAdd(&cnt[n + clampi(v.y, n)], 1);
        atomicAdd(&cnt[n + clampi(v.z, n)], 1);
        atomicAdd(&cnt[n + clampi(v.w, n)], 1);
    }
}

// ---- phase 2a: per-segment totals (SEG counters / block) -------------------
__global__ __launch_bounds__(256) void seg_sum(
    const int* __restrict__ cnt, int* __restrict__ segTot, int M)
{
    __shared__ int sh[256];
    int t = threadIdx.x;
    int i0 = blockIdx.x * SEG + t;
    int v = (i0 < M) ? cnt[i0] : 0;
    if (i0 + 256 < M) v += cnt[i0 + 256];
    sh[t] = v;
    __syncthreads();
    for (int o = 128; o; o >>= 1) {
        if (t < o) sh[t] += sh[t + o];
        __syncthreads();
    }
    if (t == 0) segTot[blockIdx.x] = sh[0];
}

// ---- phase 2b: single-block exclusive scan of segment totals ---------------
__global__ __launch_bounds__(256) void seg_scan(
    const int* __restrict__ segTot, int* __restrict__ segBase, int nseg)
{
    __shared__ int sh[256];
    int t = threadIdx.x;
    sh[t] = (t < nseg) ? segTot[t] : 0;
    __syncthreads();
    for (int o = 1; o < 256; o <<= 1) {
        int v = (t >= o) ? sh[t - o] : 0;
        __syncthreads();
        sh[t] += v;
        __syncthreads();
    }
    if (t < nseg) segBase[t] = (t == 0) ? 0 : sh[t - 1];
}

// ---- phase 2c: final exclusive scan -> rowptrC[2N+1] + cursor copy ---------
// Combined over both layers: layer1's bases continue at E automatically.
__global__ __launch_bounds__(256) void final_scan(
    const int* __restrict__ cnt, const int* __restrict__ segBase,
    int* __restrict__ rowptrC, int* __restrict__ cur, int M)
{
    __shared__ int sh[SEG];
    int t = threadIdx.x;
    int base = blockIdx.x * SEG;
    int i0 = base + t, i1 = base + t + 256;
    int v0 = (i0 < M) ? cnt[i0] : 0;
    int v1 = (i1 < M) ? cnt[i1] : 0;
    sh[t] = v0; sh[t + 256] = v1;
    __syncthreads();
    for (int o = 1; o < SEG; o <<= 1) {
        int a0 = (t >= o) ? sh[t - o] : 0;
        int a1 = (t + 256 >= o) ? sh[t + 256 - o] : 0;
        __syncthreads();
        sh[t] += a0; sh[t + 256] += a1;
        __syncthreads();
    }
    int sb = segBase[blockIdx.x];
    if (i0 < M) { int ex = sb + sh[t] - v0;       rowptrC[i0] = ex; cur[i0] = ex; }
    if (i1 < M) { int ex = sb + sh[t + 256] - v1; rowptrC[i1] = ex; cur[i1] = ex; }
    if (i0 == M - 1) rowptrC[M] = sb + sh[t];
    if (i1 == M - 1) rowptrC[M] = sb + sh[t + 256];
}

// ---- phase 3: placement -> csridx[2E] (order within a node irrelevant) -----
__global__ __launch_bounds__(256) void place_edges(
    const int* __restrict__ r0, const int* __restrict__ c0,
    const int* __restrict__ r1, const int* __restrict__ c1,
    int* __restrict__ cur, unsigned short* __restrict__ csridx, int n, int E)
{
    int gid = blockIdx.x * 256 + threadIdx.x;
    int q = E >> 2;
    if (gid < q) {
        int4 rv = ((const int4*)r0)[gid];
        int4 cv = ((const int4*)c0)[gid];
        int p;
        p = atomicAdd(&cur[clampi(cv.x, n)], 1); csridx[p] = (unsigned short)clampi(rv.x, n);
        p = atomicAdd(&cur[clampi(cv.y, n)], 1); csridx[p] = (unsigned short)clampi(rv.y, n);
        p = atomicAdd(&cur[clampi(cv.z, n)], 1); csridx[p] = (unsigned short)clampi(rv.z, n);
        p = atomicAdd(&cur[clampi(cv.w, n)], 1); csridx[p] = (unsigned short)clampi(rv.w, n);
    } else if (gid < 2 * q) {
        int i = gid - q;
        int4 rv = ((const int4*)r1)[i];
        int4 cv = ((const int4*)c1)[i];
        int p;
        p = atomicAdd(&cur[n + clampi(cv.x, n)], 1); csridx[p] = (unsigned short)clampi(rv.x, n);
        p = atomicAdd(&cur[n + clampi(cv.y, n)], 1); csridx[p] = (unsigned short)clampi(rv.y, n);
        p = atomicAdd(&cur[n + clampi(cv.z, n)], 1); csridx[p] = (unsigned short)clampi(rv.z, n);
        p = atomicAdd(&cur[n + clampi(cv.w, n)], 1); csridx[p] = (unsigned short)clampi(rv.w, n);
    }
}

// ------ GEMM precompute: P = src@W (fp16), Q = src@R + b (fp32) -------------
// mean-agg is linear, so agg(x)@W == agg(x@W). Weights register-resident;
// per-row broadcast via v_readlane. Q32 may alias src (wave reads its row
// before writing; rows are wave-disjoint).
__global__ __launch_bounds__(256) void gemm_pq_kernel(
    const float* __restrict__ src, const float* __restrict__ W,
    const float* __restrict__ R, const float* __restrict__ bvec,
    __half* __restrict__ P16, float* __restrict__ Q32, int n)
{
    int lane = threadIdx.x & 63;
    int wv = threadIdx.x >> 6;
    float wcol[FDIM], rcol[FDIM];
#pragma unroll
    for (int k = 0; k < FDIM; ++k) {
        wcol[k] = W[k * FDIM + lane];   // coalesced: lane j reads W[k][j]
        rcol[k] = R[k * FDIM + lane];
    }
    float bj = bvec[lane];
    for (int row = blockIdx.x * 4 + wv; row < n; row += gridDim.x * 4) {
        float xv = src[((size_t)row << 6) + lane];
        float accP = 0.0f, accQ = bj;
#pragma unroll
        for (int k = 0; k < FDIM; ++k) {
            float s = __uint_as_float(
                __builtin_amdgcn_readlane(__float_as_uint(xv), k));
            accP = fmaf(s, wcol[k], accP);
            accQ = fmaf(s, rcol[k], accQ);
        }
        P16[((size_t)row << 6) + lane] = __float2half(accP);
        Q32[((size_t)row << 6) + lane] = accQ;
    }
}

// ------ Fused gather (R2-verified): out = act(mean-gather(P16) + Q) ---------
// 8 lanes x float4 (16 B) per 128-B edge row; 8 edges in flight per step.
// Q read from out32 and overwritten in place (same thread, read-then-write).
template <bool RELU, bool NORM>
__global__ __launch_bounds__(256) void fused_gather_kernel(
    const int* __restrict__ rowptr, const unsigned short* __restrict__ csridx,
    const __half* __restrict__ P16, float* __restrict__ out32, int n)
{
    __shared__ __align__(16) float aRow[4][FDIM];
    int tid = threadIdx.x;
    int lane = tid & 63, w = tid >> 6;
    int g = lane >> 3;        // edge sub-group 0..7
    int q = lane & 7;         // 8-feature chunk within row

    for (int node = blockIdx.x * 4 + w; node < n; node += gridDim.x * 4) {
        int beg = rowptr[node], end = rowptr[node + 1];
        float s0 = 0.f, s1 = 0.f, s2 = 0.f, s3 = 0.f,
              s4 = 0.f, s5 = 0.f, s6 = 0.f, s7 = 0.f;
        for (int base = beg; base < end; base += 64) {
            int cnt = end - base; if (cnt > 64) cnt = 64;
            int ei = base + lane;
            int myidx = (ei < end) ? (int)csridx[ei] : 0;
            int steps = (cnt + 7) >> 3;
            for (int t = 0; t < steps; ++t) {
                int e = (t << 3) | g;
                int sidx = __shfl(myidx, e, 64);
                if (e < cnt) {
                    const float4* rp = (const float4*)(P16 + ((size_t)sidx << 6));
                    float4 vv = rp[q];                 // 8 halves = 16 B
                    __half2 h0 = *reinterpret_cast<__half2*>(&vv.x);
                    __half2 h1 = *reinterpret_cast<__half2*>(&vv.y);
                    __half2 h2 = *reinterpret_cast<__half2*>(&vv.z);
                    __half2 h3 = *reinterpret_cast<__half2*>(&vv.w);
                    float2 f0 = __half22float2(h0);
                    float2 f1 = __half22float2(h1);
                    float2 f2 = __half22float2(h2);
                    float2 f3 = __half22float2(h3);
                    s0 += f0.x; s1 += f0.y; s2 += f1.x; s3 += f1.y;
                    s4 += f2.x; s5 += f2.y; s6 += f3.x; s7 += f3.y;
                }
            }
        }
#pragma unroll
        for (int o = 8; o < 64; o <<= 1) {
            s0 += __shfl_xor(s0, o, 64);
            s1 += __shfl_xor(s1, o, 64);
            s2 += __shfl_xor(s2, o, 64);
            s3 += __shfl_xor(s3, o, 64);
            s4 += __shfl_xor(s4, o, 64);
            s5 += __shfl_xor(s5, o, 64);
            s6 += __shfl_xor(s6, o, 64);
            s7 += __shfl_xor(s7, o, 64);
        }
        float dinv = 1.0f / fmaxf((float)(end - beg), 1.0f);
        if (g == 0) {
            float4* ar = (float4*)&aRow[w][q * 8];
            ar[0] = make_float4(s0 * dinv, s1 * dinv, s2 * dinv, s3 * dinv);
            ar[1] = make_float4(s4 * dinv, s5 * dinv, s6 * dinv, s7 * dinv);
        }
        // wave-local LDS RAW: ordered within the wave, no barrier needed
        float acc = aRow[w][lane] + out32[((size_t)node << 6) + lane];
        if (RELU) acc = fmaxf(acc, 0.0f);
        if (NORM) {
            float ss = acc * acc;
#pragma unroll
            for (int o = 32; o; o >>= 1) ss += __shfl_xor(ss, o, 64);
            acc *= 1.0f / fmaxf(sqrtf(ss), 1e-12f);
        }
        out32[((size_t)node << 6) + lane] = acc;
    }
}

// ----------------- Atomic scatter path (fallback, 13.0 MB ws) ---------------
__global__ __launch_bounds__(256) void scatter_kernel(
    const float* __restrict__ src, const int* __restrict__ rows, const int* __restrict__ cols,
    float* __restrict__ agg, float* __restrict__ deg, int n, long long total)
{
    long long gid = (long long)blockIdx.x * 256 + threadIdx.x;
    if (gid >= total) return;
    int e = (int)(gid >> 6);
    int f = (int)(gid & 63);
    int r = clampi(rows[e], n), c = clampi(cols[e], n);
    atomicAdd(&agg[(long long)c * FDIM + f], src[(long long)r * FDIM + f]);
    if (f == 0) atomicAdd(&deg[c], 1.0f);
}

template <bool RELU, bool NORM>
__global__ __launch_bounds__(256) void dense_kernel(
    const float* __restrict__ agg, const float* __restrict__ deg, const float* __restrict__ x,
    const float* __restrict__ W, const float* __restrict__ b,
    const float* __restrict__ R, float* __restrict__ out, int n)
{
    __shared__ float Ws[FDIM][FDIM];
    __shared__ float Rs[FDIM][FDIM];
    __shared__ float bs[FDIM];
    __shared__ float aRow[4][FDIM];
    __shared__ float xRow[4][FDIM];
    int tid = threadIdx.x;
    for (int i = tid; i < FDIM * FDIM; i += 256) {
        Ws[i >> 6][i & 63] = W[i];
        Rs[i >> 6][i & 63] = R[i];
    }
    if (tid < FDIM) bs[tid] = b[tid];
    int j = tid & 63, r = tid >> 6;
    int row = blockIdx.x * 4 + r;
    if (row < n) {
        float d = fmaxf(deg[row], 1.0f);
        aRow[r][j] = agg[(long long)row * FDIM + j] / d;
        xRow[r][j] = x[(long long)row * FDIM + j];
    }
    __syncthreads();
    if (row >= n) return;
    float acc = bs[j];
#pragma unroll
    for (int k = 0; k < FDIM; ++k)
        acc = fmaf(aRow[r][k], Ws[k][j], fmaf(xRow[r][k], Rs[k][j], acc));
    if (RELU) acc = fmaxf(acc, 0.0f);
    if (NORM) {
        float ss = acc * acc;
#pragma unroll
        for (int o = 32; o; o >>= 1) ss += __shfl_xor(ss, o, 64);
        acc *= 1.0f / fmaxf(sqrtf(ss), 1e-12f);
    }
    out[(long long)row * FDIM + j] = acc;
}

// ---------------------------------------------------------------------------
extern "C" void kernel_launch(void* const* d_in, const int* in_sizes, int n_in,
                              void* d_out, int out_size, void* d_ws, size_t ws_size,
                              hipStream_t stream)
{
    const float* x  = (const float*)d_in[0];
    const int*   e0 = (const int*)d_in[1];
    const int*   e1 = (const int*)d_in[2];
    const float* W1 = (const float*)d_in[3];
    const float* b1 = (const float*)d_in[4];
    const float* R1 = (const float*)d_in[5];
    const float* W2 = (const float*)d_in[6];
    const float* b2 = (const float*)d_in[7];
    const float* R2 = (const float*)d_in[8];
    float* out = (float*)d_out;

    const int N = in_sizes[0] / FDIM;     // 50000
    const int E = in_sizes[1] / 2;        // 1600000

    const int M = 2 * N;                  // combined counters, both layers
    const int nseg = (M + SEG - 1) / SEG; // scan segments
    const int GATHER_BLOCKS = 2048;       // 1 KB LDS, VGPR ~64
    const int GEMM_BLOCKS = 1024;         // ~12 rows/wave, amortizes reg-W load

    // Workspace (16-B aligned): cnt[2N] | cur[2N] | rowptrC[2N+1] |
    // segTot[nseg] | segBase[nseg] | csridx[2E] u16 | P16[N*64] half  (~15 MB)
    auto align16 = [](size_t v) { return (v + 15) & ~(size_t)15; };
    size_t off = 0;
    size_t o_cnt   = off; off = align16(off + (size_t)M * 4);
    size_t o_cur   = off; off = align16(off + (size_t)M * 4);
    size_t o_rowp  = off; off = align16(off + (size_t)(M + 1) * 4);
    size_t o_stot  = off; off = align16(off + (size_t)nseg * 4);
    size_t o_sbase = off; off = align16(off + (size_t)nseg * 4);
    size_t o_csr16 = off; off = align16(off + (size_t)2 * E * 2);
    size_t o_p16   = off; off = align16(off + (size_t)N * FDIM * 2);
    const size_t need1 = off;

    const bool ok1 = (ws_size >= need1) && (N <= 65536) && (nseg <= 256) &&
                     ((E & 3) == 0);

    if (ok1) {
        char* wsb = (char*)d_ws;
        int*             cnt     = (int*)(wsb + o_cnt);
        int*             cur     = (int*)(wsb + o_cur);
        int*             rowptrC = (int*)(wsb + o_rowp);
        int*             segTot  = (int*)(wsb + o_stot);
        int*             segBase = (int*)(wsb + o_sbase);
        unsigned short*  csridx  = (unsigned short*)(wsb + o_csr16);
        __half*          P16     = (__half*)(wsb + o_p16);

        hipMemsetAsync(cnt, 0, (size_t)M * sizeof(int), stream);

        // ---- Layer 1 GEMM: P16 = x@W1 (fp16), Q1 = x@R1 + b1 -> out ----
        gemm_pq_kernel<<<GEMM_BLOCKS, 256, 0, stream>>>(
            x, W1, R1, b1, P16, out, N);

        // ---- CSR build, both layers (edges independent of features) ----
        const int cblocks = (E / 4 + 255) / 256;
        count_edges<<<cblocks, 256, 0, stream>>>(e0 + E, e1 + E, cnt, N, E);
        seg_sum<<<nseg, 256, 0, stream>>>(cnt, segTot, M);
        seg_scan<<<1, 256, 0, stream>>>(segTot, segBase, nseg);
        final_scan<<<nseg, 256, 0, stream>>>(cnt, segBase, rowptrC, cur, M);
        const int pblocks = (2 * (E / 4) + 255) / 256;
        place_edges<<<pblocks, 256, 0, stream>>>(e0, e0 + E, e1, e1 + E,
                                                 cur, csridx, N, E);

        // ---- Layer 1 gather: h = relu(mean-gather(P1) + Q1), in place ----
        fused_gather_kernel<true, false><<<GATHER_BLOCKS, 256, 0, stream>>>(
            rowptrC, csridx, P16, out, N);

        // ---- Layer 2 GEMM: P16 = h@W2, Q2 = h@R2 + b2 (in-place) ----
        gemm_pq_kernel<<<GEMM_BLOCKS, 256, 0, stream>>>(
            out, W2, R2, b2, P16, out, N);

        // ---- Layer 2 gather: out = normalize(mean-gather(P2) + Q2) ----
        fused_gather_kernel<false, true><<<GATHER_BLOCKS, 256, 0, stream>>>(
            rowptrC + N, csridx, P16, out, N);
    } else {
        // Fallback: atomic scatter path (round-3, verified)
        float* agg = (float*)d_ws;
        float* deg = agg + (long long)N * FDIM;
        float* h = out;
        const long long total = (long long)E * FDIM;
        const int sblocks = (int)((total + 255) / 256);
        const int dblocks = (N + 3) / 4;

        hipMemsetAsync(agg, 0, ((size_t)N * FDIM + N) * sizeof(float), stream);
        scatter_kernel<<<sblocks, 256, 0, stream>>>(x, e0, e0 + E, agg, deg, N, total);
        dense_kernel<true, false><<<dblocks, 256, 0, stream>>>(agg, deg, x, W1, b1, R1, h, N);

        hipMemsetAsync(agg, 0, ((size_t)N * FDIM + N) * sizeof(float), stream);
        scatter_kernel<<<sblocks, 256, 0, stream>>>(h, e1, e1 + E, agg, deg, N, total);
        dense_kernel<false, true><<<dblocks, 256, 0, stream>>>(agg, deg, h, W2, b2, R2, out, N);
    }
}